// Round 10
// baseline (246.911 us; speedup 1.0000x reference)
//
#include <hip/hip_runtime.h>

typedef __attribute__((ext_vector_type(8))) __bf16 bf16x8;
typedef __attribute__((ext_vector_type(4))) float floatx4;

#define M_TOT 256
#define K_TOT 5120
#define N_TOT 13824
#define NBLK  320      // K/16
#define BN    128
#define KSPLIT 4
#define KCH   1280     // K / KSPLIT
#define KSUP  128      // K per LDS A-chunk
#define NSUP  10       // KCH / KSUP
#define NSTEP 40       // KCH / 32 (32-K steps)

#define GLOAD_LDS16(g, l)                                                     \
  __builtin_amdgcn_global_load_lds(                                           \
      (const __attribute__((address_space(1))) void*)(g),                     \
      (__attribute__((address_space(3))) void*)(l), 16, 0, 0)

static __device__ __forceinline__ float bf16r(float v) { return (float)(__bf16)v; }

static __device__ __forceinline__ float fp4round(float v) {
  float a = fabsf(v), q;
  if      (a < 0.25f) q = 0.0f;
  else if (a < 0.75f) q = 0.5f;
  else if (a < 1.25f) q = 1.0f;
  else if (a < 1.75f) q = 1.5f;
  else if (a < 2.5f)  q = 2.0f;
  else if (a < 3.5f)  q = 3.0f;
  else if (a < 5.0f)  q = 4.0f;
  else                q = 6.0f;
  return copysignf(q, v);
}

// round f (in [0,448]) to fp8 e4m3fn, RNE — exact pow2 arithmetic
static __device__ __forceinline__ float cvt_e4m3(float f) {
  if (f < 0.015625f) return rintf(f * 512.0f) * 0.001953125f;  // subnormal, q=2^-9
  int e = (int)(__float_as_uint(f) >> 23) - 127;
  float q = __uint_as_float((unsigned)(e - 3 + 127) << 23);    // 2^(e-3)
  return rintf(f / q) * q;                                     // exact div/mul by pow2
}

// ------- kernel 1: zero output (atomic target) + global amax of bf16(x) -------
__global__ void k_prep(const float* __restrict__ x, unsigned* __restrict__ amax_bits,
                       float4* __restrict__ out4) {
  int idx = blockIdx.x * blockDim.x + threadIdx.x;   // 327680 threads
#pragma unroll 1
  for (int j = idx; j < 884736; j += 327680) out4[j] = (float4){0.f, 0.f, 0.f, 0.f};
  float4 v = ((const float4*)x)[idx];                // exact cover of x
  float m = fmaxf(fmaxf(fabsf(bf16r(v.x)), fabsf(bf16r(v.y))),
                  fmaxf(fabsf(bf16r(v.z)), fabsf(bf16r(v.w))));
#pragma unroll
  for (int off = 32; off; off >>= 1) m = fmaxf(m, __shfl_xor(m, off));
  if ((threadIdx.x & 63) == 0) atomicMax(amax_bits, __float_as_uint(m));
}

// ------- kernel 2: activation nvfp4 quant, folded to bf16 a_u = q*s -------
__global__ void k_aquant(const float* __restrict__ x,
                         const unsigned* __restrict__ amax_bits,
                         __bf16* __restrict__ au) {
  int idx = blockIdx.x * blockDim.x + threadIdx.x;  // 0..81919 (m*320+b)
  int m = idx / NBLK;
  int b = idx - m * NBLK;
  float amax = __uint_as_float(*amax_bits);
  float gs  = 2688.0f / amax;   // (448*6)/amax, matches ref op order
  float gs6 = gs / 6.0f;
  const float4* xp = (const float4*)(x + m * K_TOT + b * 16);
  float4 v0 = xp[0], v1 = xp[1], v2 = xp[2], v3 = xp[3];
  float xv[16];
  xv[0]=bf16r(v0.x); xv[1]=bf16r(v0.y); xv[2]=bf16r(v0.z); xv[3]=bf16r(v0.w);
  xv[4]=bf16r(v1.x); xv[5]=bf16r(v1.y); xv[6]=bf16r(v1.z); xv[7]=bf16r(v1.w);
  xv[8]=bf16r(v2.x); xv[9]=bf16r(v2.y); xv[10]=bf16r(v2.z); xv[11]=bf16r(v2.w);
  xv[12]=bf16r(v3.x); xv[13]=bf16r(v3.y); xv[14]=bf16r(v3.z); xv[15]=bf16r(v3.w);
  float am = 0.f;
#pragma unroll
  for (int j = 0; j < 16; ++j) am = fmaxf(am, fabsf(xv[j]));
  float s = cvt_e4m3(fminf(am * gs6, 448.0f));
  float g = gs / ((s == 0.f) ? 1.f : s);
  bf16x8 p0, p1;
#pragma unroll
  for (int j = 0; j < 8; ++j) p0[j] = (__bf16)(fp4round(xv[j] * g) * s);      // exact in bf16
#pragma unroll
  for (int j = 0; j < 8; ++j) p1[j] = (__bf16)(fp4round(xv[8 + j] * g) * s);
  bf16x8* dst = (bf16x8*)(au + (size_t)idx * 16);
  dst[0] = p0; dst[1] = p1;
}

// -------- kernel 3: deep-ring GEMM. BM=256, BN=128, 1024 thr = 16 waves (2m x 8n) --------
// A: [256 x 128K] chunk double-buffered in LDS (2x64KB), one barrier per chunk.
// W: per-lane 4-slot register ring (1 chunk lookahead), compiler-counted vmcnt,
//    never drained. A-landed waits are FIFO-exact: sched_barrier pins A oldest,
//    then vmcnt(12) (= the 12 W VMEM issued after A) retires A regardless of
//    scheduler reordering of the W stream.
// A staging obeys the gload_lds contract: WAVE-UNIFORM LDS dst (wv*4096+i*1024),
// hardware places lane l at +l*16; the XOR swizzle is applied on the per-lane
// GLOBAL source column instead (rule #21).
__global__ __launch_bounds__(1024, 4) void k_gemm(
    const __bf16* __restrict__ au,      // [256][5120] bf16 (scales folded)
    const float*  __restrict__ w,       // [N][K] fp4 values in f32
    const float*  __restrict__ wsc,     // [N][320] fp8-representable scales
    const unsigned* __restrict__ amax_bits,
    const float*  __restrict__ wgs,     // scalar
    const float*  __restrict__ bias,    // [N]
    float* __restrict__ out)            // [256][13824], pre-zeroed
{
  __shared__ __bf16 Ab[2][M_TOT * KSUP];   // 2 x 64 KB

  const int tid  = threadIdx.x;
  const int lane = tid & 63;
  const int wv   = tid >> 6;     // 0..15
  const int wm   = wv >> 3;      // 0..1 (128-row half)
  const int wn   = wv & 7;       // 0..7 (16-col slab)

  const int s     = blockIdx.x & 3;
  const int n0    = (blockIdx.x >> 2) * BN;
  const int kbase = s * KCH;

  const int hi  = lane >> 4;     // 0..3
  const int r15 = lane & 15;

  // A staging geometry: LDS phys addr = wv*4096 + i*1024 + lane*16
  //   -> row = wv*16 + i*4 + (lane>>4), slot = lane&15.
  // LDS[row][slot] must hold logical chunk slot^(row&15) of row, so lane
  // fetches global chunk g = (lane&15) ^ ((i*4 + (lane>>4)) & 15).
  const int arow0 = wv * 16 + hi;          // + i*4
  const int l15   = lane & 15;

  // W per-lane: row n0+wn*16+r15, k = t*32 + hi*8 .. +8
  const int nrow = n0 + wn * 16 + r15;
  const float* wrow = w   + (size_t)nrow * K_TOT + kbase + hi * 8;
  const float* wsp  = wsc + (size_t)nrow * NBLK + s * (KCH / 16);
  const int hi2 = hi >> 1;

  floatx4 acc[8];
#pragma unroll
  for (int fm = 0; fm < 8; ++fm) acc[fm] = (floatx4){0.f, 0.f, 0.f, 0.f};

  struct Slot { float4 a, b; float sc; };
  Slot w0, w1, w2, w3;

  auto issueA = [&](int c, int buf) {
    char* dst = (char*)(&Ab[buf][0]) + wv * 4096;   // wave-uniform base
#pragma unroll
    for (int i = 0; i < 4; ++i) {
      const int row = arow0 + i * 4;
      const int g   = l15 ^ (row & 15);
      const __bf16* src = au + (size_t)row * K_TOT + kbase + c * KSUP + g * 8;
      GLOAD_LDS16(src, dst + i * 1024);
    }
  };
  auto issueW = [&](Slot& sl, int t) {
    const float* p = wrow + t * 32;
    sl.a  = *(const float4*)p;
    sl.b  = *(const float4*)(p + 4);
    sl.sc = wsp[t * 2 + hi2];
  };
  auto stepC = [&](Slot& sl, int buf, int j, int tnext) {
    bf16x8 bfr;                      // compiler inserts counted vmcnt before reads
    bfr[0] = (__bf16)(sl.a.x * sl.sc); bfr[1] = (__bf16)(sl.a.y * sl.sc);
    bfr[2] = (__bf16)(sl.a.z * sl.sc); bfr[3] = (__bf16)(sl.a.w * sl.sc);
    bfr[4] = (__bf16)(sl.b.x * sl.sc); bfr[5] = (__bf16)(sl.b.y * sl.sc);
    bfr[6] = (__bf16)(sl.b.z * sl.sc); bfr[7] = (__bf16)(sl.b.w * sl.sc);
    if (tnext < NSTEP) issueW(sl, tnext);
    const char* pA = (const char*)(&Ab[buf][0]) + (wm * 128 + r15) * 256;
#pragma unroll
    for (int fm = 0; fm < 8; ++fm) {
      bf16x8 af = *(const bf16x8*)(pA + fm * 4096 + (((j * 4 + hi) ^ r15) << 4));
      acc[fm] = __builtin_amdgcn_mfma_f32_16x16x32_bf16(af, bfr, acc[fm], 0, 0, 0);
    }
  };

  // prologue: A(0) pinned oldest, ring-fill W(0..3), wait A(0) (12 W after it)
  issueA(0, 0);
  __builtin_amdgcn_sched_barrier(0);
  issueW(w0, 0); issueW(w1, 1); issueW(w2, 2); issueW(w3, 3);
  asm volatile("s_waitcnt vmcnt(12)" ::: "memory");
  __builtin_amdgcn_sched_barrier(0);
  __builtin_amdgcn_s_barrier();
  __builtin_amdgcn_sched_barrier(0);

#pragma unroll 1
  for (int c = 0; c < NSUP; ++c) {
    const int buf = c & 1;
    const int tb = c * 4;
    if (c + 1 < NSUP) {
      issueA(c + 1, buf ^ 1);          // into the buffer chunk c-1's readers freed
      __builtin_amdgcn_sched_barrier(0);
    }
    stepC(w0, buf, 0, tb + 4);
    stepC(w1, buf, 1, tb + 5);
    stepC(w2, buf, 2, tb + 6);
    stepC(w3, buf, 3, tb + 7);
    if (c + 1 < NSUP) {
      // A(c+1) retired (the 12 W of this chunk were issued after it);
      // my ds_reads of buf done; then rendezvous.
      asm volatile("s_waitcnt vmcnt(12) lgkmcnt(0)" ::: "memory");
      __builtin_amdgcn_sched_barrier(0);
      __builtin_amdgcn_s_barrier();
      __builtin_amdgcn_sched_barrier(0);
    }
  }

  // epilogue: atomic accumulate (out pre-zeroed; bias folded into split 0)
  float amax = __uint_as_float(*amax_bits);
  float a_gs = 2688.0f / amax;
  float alpha = 1.0f / (a_gs * wgs[0]);
  const int ncol = n0 + wn * 16 + r15;
  const float bb = (s == 0) ? bias[ncol] : 0.0f;
#pragma unroll
  for (int fm = 0; fm < 8; ++fm) {
    int mrow = wm * 128 + fm * 16 + hi * 4;
#pragma unroll
    for (int j = 0; j < 4; ++j)
      atomicAdd(&out[(size_t)(mrow + j) * N_TOT + ncol],
                acc[fm][j] * alpha + bb);
  }
}

extern "C" void kernel_launch(void* const* d_in, const int* in_sizes, int n_in,
                              void* d_out, int out_size, void* d_ws, size_t ws_size,
                              hipStream_t stream) {
  const float* x    = (const float*)d_in[0];
  const float* wq   = (const float*)d_in[1];
  const float* wsc  = (const float*)d_in[2];
  const float* wgs  = (const float*)d_in[3];
  const float* bias = (const float*)d_in[4];
  float* out = (float*)d_out;

  unsigned* amax = (unsigned*)d_ws;
  __bf16* au = (__bf16*)((char*)d_ws + 256);   // 2.62 MB scratch

  hipMemsetAsync(d_ws, 0, 4, stream);
  k_prep<<<dim3(1280), dim3(256), 0, stream>>>(x, amax, (float4*)out);
  k_aquant<<<dim3(M_TOT * NBLK / 256), dim3(256), 0, stream>>>(x, amax, au);
  k_gemm<<<dim3((N_TOT / BN) * KSPLIT), dim3(1024), 0, stream>>>(au, wq, wsc, amax, wgs, bias, out);
}

// Round 11
// 237.887 us; speedup vs baseline: 1.0379x; 1.0379x over previous
//
#include <hip/hip_runtime.h>

typedef __attribute__((ext_vector_type(8))) __bf16 bf16x8;
typedef __attribute__((ext_vector_type(4))) float floatx4;

#define M_TOT 256
#define K_TOT 5120
#define N_TOT 13824
#define NBLK  320      // K/16
#define BN    64
#define BK    64
#define KSPLIT 4
#define KCH   1280     // K / KSPLIT
#define NSTEP 20       // KCH / BK
#define KSTEPS 80      // K / BK total
#define NTILES 216     // N / BN

#define GLOAD_LDS16(g, l)                                                     \
  __builtin_amdgcn_global_load_lds(                                           \
      (const __attribute__((address_space(1))) void*)(g),                     \
      (__attribute__((address_space(3))) void*)(l), 16, 0, 0)

static __device__ __forceinline__ float bf16r(float v) { return (float)(__bf16)v; }

static __device__ __forceinline__ float fp4round(float v) {
  float a = fabsf(v), q;
  if      (a < 0.25f) q = 0.0f;
  else if (a < 0.75f) q = 0.5f;
  else if (a < 1.25f) q = 1.0f;
  else if (a < 1.75f) q = 1.5f;
  else if (a < 2.5f)  q = 2.0f;
  else if (a < 3.5f)  q = 3.0f;
  else if (a < 5.0f)  q = 4.0f;
  else                q = 6.0f;
  return copysignf(q, v);
}

// round f (in [0,448]) to fp8 e4m3fn, RNE — exact pow2 arithmetic
static __device__ __forceinline__ float cvt_e4m3(float f) {
  if (f < 0.015625f) return rintf(f * 512.0f) * 0.001953125f;  // subnormal, q=2^-9
  int e = (int)(__float_as_uint(f) >> 23) - 127;
  float q = __uint_as_float((unsigned)(e - 3 + 127) << 23);    // 2^(e-3)
  return rintf(f / q) * q;                                     // exact div/mul by pow2
}

// ---- kernel 0: pure-stream W dequant into pre-swizzled GEMM tile layout ----
// wt layout: [ntile 216][kstep 80][row 64][chsw 8][8 bf16], where (row, chsw)
// holds logical 8-elem chunk (chsw ^ (row&7)) of weight row ntile*64+row,
// k-range kstep*64 + lch*8. One thread per output 16 B chunk.
__global__ void k_wdeq(const float* __restrict__ w, const float* __restrict__ wsc,
                       __bf16* __restrict__ wt) {
  int c = blockIdx.x * blockDim.x + threadIdx.x;   // 0 .. 8,847,359
  int chsw = c & 7;
  int row  = (c >> 3) & 63;
  int g    = c >> 9;                 // ntile*80 + t
  int t    = g % KSTEPS;
  int nt   = g / KSTEPS;
  int lch  = chsw ^ (row & 7);
  int n    = nt * 64 + row;
  const float* p = w + (size_t)n * K_TOT + t * 64 + lch * 8;
  float sc = wsc[(size_t)n * NBLK + t * 4 + (lch >> 1)];
  float4 a = *(const float4*)p, b = *(const float4*)(p + 4);
  bf16x8 o;
  o[0] = (__bf16)(a.x * sc); o[1] = (__bf16)(a.y * sc);
  o[2] = (__bf16)(a.z * sc); o[3] = (__bf16)(a.w * sc);
  o[4] = (__bf16)(b.x * sc); o[5] = (__bf16)(b.y * sc);
  o[6] = (__bf16)(b.z * sc); o[7] = (__bf16)(b.w * sc);   // exact in bf16
  *(bf16x8*)(wt + (size_t)c * 8) = o;
}

// ------- kernel 1: zero output (atomic target) + global amax of bf16(x) -------
__global__ void k_prep(const float* __restrict__ x, unsigned* __restrict__ amax_bits,
                       float4* __restrict__ out4) {
  int idx = blockIdx.x * blockDim.x + threadIdx.x;   // 327680 threads
#pragma unroll 1
  for (int j = idx; j < 884736; j += 327680) out4[j] = (float4){0.f, 0.f, 0.f, 0.f};
  float4 v = ((const float4*)x)[idx];                // exact cover of x
  float m = fmaxf(fmaxf(fabsf(bf16r(v.x)), fabsf(bf16r(v.y))),
                  fmaxf(fabsf(bf16r(v.z)), fabsf(bf16r(v.w))));
#pragma unroll
  for (int off = 32; off; off >>= 1) m = fmaxf(m, __shfl_xor(m, off));
  if ((threadIdx.x & 63) == 0) atomicMax(amax_bits, __float_as_uint(m));
}

// ------- kernel 2: activation nvfp4 quant -> au in pre-swizzled tile layout -------
// au layout: [kstep 80][row 256][chsw 8][8 bf16]; (row,chsw) holds logical
// chunk (chsw ^ (row&7)).
__global__ void k_aquant(const float* __restrict__ x,
                         const unsigned* __restrict__ amax_bits,
                         __bf16* __restrict__ au) {
  int idx = blockIdx.x * blockDim.x + threadIdx.x;  // 0..81919 (m*320+b)
  int m = idx / NBLK;
  int b = idx - m * NBLK;
  float amax = __uint_as_float(*amax_bits);
  float gs  = 2688.0f / amax;   // (448*6)/amax, matches ref op order
  float gs6 = gs / 6.0f;
  const float4* xp = (const float4*)(x + m * K_TOT + b * 16);
  float4 v0 = xp[0], v1 = xp[1], v2 = xp[2], v3 = xp[3];
  float xv[16];
  xv[0]=bf16r(v0.x); xv[1]=bf16r(v0.y); xv[2]=bf16r(v0.z); xv[3]=bf16r(v0.w);
  xv[4]=bf16r(v1.x); xv[5]=bf16r(v1.y); xv[6]=bf16r(v1.z); xv[7]=bf16r(v1.w);
  xv[8]=bf16r(v2.x); xv[9]=bf16r(v2.y); xv[10]=bf16r(v2.z); xv[11]=bf16r(v2.w);
  xv[12]=bf16r(v3.x); xv[13]=bf16r(v3.y); xv[14]=bf16r(v3.z); xv[15]=bf16r(v3.w);
  float am = 0.f;
#pragma unroll
  for (int j = 0; j < 16; ++j) am = fmaxf(am, fabsf(xv[j]));
  float s = cvt_e4m3(fminf(am * gs6, 448.0f));
  float g = gs / ((s == 0.f) ? 1.f : s);
  bf16x8 p0, p1;
#pragma unroll
  for (int j = 0; j < 8; ++j) p0[j] = (__bf16)(fp4round(xv[j] * g) * s);      // exact in bf16
#pragma unroll
  for (int j = 0; j < 8; ++j) p1[j] = (__bf16)(fp4round(xv[8 + j] * g) * s);
  int t = b >> 2, pr = b & 3;
  __bf16* base = au + (size_t)(t * 256 + m) * 64;
  *(bf16x8*)(base + (((2 * pr)     ^ (m & 7)) * 8)) = p0;
  *(bf16x8*)(base + (((2 * pr + 1) ^ (m & 7)) * 8)) = p1;
}

// ------- kernel 3: lean bf16 MFMA GEMM, all staging via linear global_load_lds -------
// BM=256 (all M), BN=64, BK=64, 512 thr (8 waves: 4M x 2N), wave tile 64x32.
// Per wave per step: 4 A gloads + 1 B gload, each 1 KB fully contiguous.
__global__ __launch_bounds__(512, 4) void k_gemm(
    const __bf16* __restrict__ au,      // tiled [80][256][8][8]
    const __bf16* __restrict__ wt,      // tiled [216][80][64][8][8]
    const unsigned* __restrict__ amax_bits,
    const float*  __restrict__ wgs,     // scalar
    const float*  __restrict__ bias,    // [N]
    float* __restrict__ out)            // [256][13824], pre-zeroed
{
  __shared__ __bf16 Ab[2][M_TOT * BK];  // 2 x 32 KB
  __shared__ __bf16 Bb[2][BN * BK];     // 2 x 8 KB

  const int tid  = threadIdx.x;
  const int lane = tid & 63;
  const int wv   = tid >> 6;     // 0..7
  const int wm   = wv >> 1;      // 0..3 (64-row group)
  const int wn   = wv & 1;       // 0..1 (32-col group)

  const int s    = blockIdx.x & (KSPLIT - 1);
  const int nt   = blockIdx.x >> 2;
  const int n0   = nt * BN;
  const int s20  = s * NSTEP;    // base k-step

  const int sw  = (lane & 7) << 4;
  const int hi  = lane >> 4;
  const int r15 = lane & 15;

  // linear staging sources (advance by constant per step)
  const __bf16* asrc = au + (size_t)s20 * 16384 + (wv * 32) * 64 + lane * 8;
  const __bf16* bsrc = wt + ((size_t)nt * KSTEPS + s20) * 4096 + wv * 512 + lane * 8;

  floatx4 acc[4][2];
#pragma unroll
  for (int fm = 0; fm < 4; ++fm)
#pragma unroll
    for (int fn = 0; fn < 2; ++fn) acc[fm][fn] = (floatx4){0.f, 0.f, 0.f, 0.f};

  auto issueAB = [&](int t, int buf) {
    const __bf16* a = asrc + (size_t)t * 16384;
    char* dA = (char*)(&Ab[buf][0]) + wv * 4096;
#pragma unroll
    for (int i = 0; i < 4; ++i)
      GLOAD_LDS16(a + i * 512, dA + i * 1024);
    GLOAD_LDS16(bsrc + (size_t)t * 4096, (char*)(&Bb[buf][0]) + wv * 1024);
  };
  auto compute = [&](int buf) {
    char* pA = (char*)(&Ab[buf][0]);
    char* pB = (char*)(&Bb[buf][0]);
#pragma unroll
    for (int ss = 0; ss < 2; ++ss) {
      const int cb = ss * 64 + hi * 16;
      bf16x8 af[4], bfr[2];
#pragma unroll
      for (int fm = 0; fm < 4; ++fm)
        af[fm] = *(const bf16x8*)(pA + (wm * 64 + fm * 16 + r15) * 128 + (cb ^ sw));
#pragma unroll
      for (int fn = 0; fn < 2; ++fn)
        bfr[fn] = *(const bf16x8*)(pB + (wn * 32 + fn * 16 + r15) * 128 + (cb ^ sw));
#pragma unroll
      for (int fm = 0; fm < 4; ++fm)
#pragma unroll
        for (int fn = 0; fn < 2; ++fn)
          acc[fm][fn] = __builtin_amdgcn_mfma_f32_16x16x32_bf16(af[fm], bfr[fn], acc[fm][fn], 0, 0, 0);
    }
  };

  // 2-phase pipeline (R3 structure)
  int buf = 0;
  issueAB(0, 0);
  __syncthreads();
#pragma unroll 1
  for (int t = 0; t < NSTEP; ++t) {
    if (t + 1 < NSTEP) issueAB(t + 1, buf ^ 1);
    compute(buf);
    __syncthreads();
    buf ^= 1;
  }

  // epilogue: atomic accumulate (out pre-zeroed; bias folded into split 0)
  float amax = __uint_as_float(*amax_bits);
  float a_gs = 2688.0f / amax;
  float alpha = 1.0f / (a_gs * wgs[0]);
#pragma unroll
  for (int fm = 0; fm < 4; ++fm) {
#pragma unroll
    for (int fn = 0; fn < 2; ++fn) {
      int mrow = wm * 64 + fm * 16 + hi * 4;
      int ncol = n0 + wn * 32 + fn * 16 + r15;
      float bb = (s == 0) ? bias[ncol] : 0.0f;
#pragma unroll
      for (int j = 0; j < 4; ++j)
        atomicAdd(&out[(size_t)(mrow + j) * N_TOT + ncol],
                  acc[fm][fn][j] * alpha + bb);
    }
  }
}

extern "C" void kernel_launch(void* const* d_in, const int* in_sizes, int n_in,
                              void* d_out, int out_size, void* d_ws, size_t ws_size,
                              hipStream_t stream) {
  const float* x    = (const float*)d_in[0];
  const float* wq   = (const float*)d_in[1];
  const float* wsc  = (const float*)d_in[2];
  const float* wgs  = (const float*)d_in[3];
  const float* bias = (const float*)d_in[4];
  float* out = (float*)d_out;

  unsigned* amax = (unsigned*)d_ws;
  __bf16* au = (__bf16*)((char*)d_ws + 256);                 // 2.62 MB
  __bf16* wt = (__bf16*)((char*)d_ws + (4ull << 20));        // 141.6 MB

  hipMemsetAsync(d_ws, 0, 4, stream);
  k_wdeq<<<dim3(N_TOT * K_TOT / 8 / 256), dim3(256), 0, stream>>>(wq, wsc, wt);
  k_prep<<<dim3(1280), dim3(256), 0, stream>>>(x, amax, (float4*)out);
  k_aquant<<<dim3(M_TOT * NBLK / 256), dim3(256), 0, stream>>>(x, amax, au);
  k_gemm<<<dim3(NTILES * KSPLIT), dim3(512), 0, stream>>>(au, wt, amax, wgs, bias, out);
}